// Round 9
// baseline (65.789 us; speedup 1.0000x reference)
//
#include <hip/hip_runtime.h>
#include <math.h>

constexpr int kN = 4096;
constexpr int kD = 4;
constexpr int kB = 2;
constexpr int kBlock = 256;
constexpr int kTJ = 512;               // j per LDS tile
constexpr int kTiles = kN / kTJ;       // 8
constexpr int kStages = kN / 256;      // 16 (1 row/wave, 4 j/lane/stage)

// Precompute sin/cos(theta) as float4-per-j tables: sinT[b*N+j] = {s_d0..s_d3}.
__global__ __launch_bounds__(256)
void table_kernel(const float* __restrict__ theta,
                  float4* __restrict__ sinT, float4* __restrict__ cosT)
{
    const int idx = blockIdx.x * blockDim.x + threadIdx.x;   // over B*N
    const float4 t4 = *reinterpret_cast<const float4*>(&theta[(size_t)idx * kD]);
    float4 s4, c4;
    __sincosf(t4.x, &s4.x, &c4.x);
    __sincosf(t4.y, &s4.y, &c4.y);
    __sincosf(t4.z, &s4.z, &c4.z);
    __sincosf(t4.w, &s4.w, &c4.w);
    sinT[idx] = s4;
    cosT[idx] = c4;
}

// 1 row/wave (max TLP: 2048 blocks = 8/CU), tables LDS-tiled (16 KB,
// u-permuted conflict-free), W/alpha register pipeline 2 stages deep.
template <bool USE_TABLE>
__global__ __launch_bounds__(kBlock)
void kuramoto_kernel(const float* __restrict__ theta,
                     const float* __restrict__ gam,
                     const float* __restrict__ W,
                     const float* __restrict__ alpha,
                     const float4* __restrict__ sinT,
                     const float4* __restrict__ cosT,
                     float* __restrict__ out)
{
    __shared__ __align__(16) float4 sS[4][kTJ / 4];   // 8 KB
    __shared__ __align__(16) float4 sC[4][kTJ / 4];   // 8 KB

    const int tid  = threadIdx.x;
    const int wave = tid >> 6;
    const int lane = tid & 63;

    const int row = blockIdx.x * 4 + wave;            // global row = b*N + i
    const int b   = row >> 12;

    const float* __restrict__ Wrow = W     + (size_t)row * kN;
    const float* __restrict__ Arow = alpha + (size_t)row * kN;
    const float4* __restrict__ sT = sinT + (size_t)b * kN;
    const float4* __restrict__ cT = cosT + (size_t)b * kN;
    const float* __restrict__ thetaB = theta + (size_t)b * kN * kD;

    float U[4] = {0, 0, 0, 0}, V[4] = {0, 0, 0, 0};

    auto pf = [&](int s, float4& w4, float4& a4) {
        const int j = s * 256 + lane * 4;
        w4 = *reinterpret_cast<const float4*>(&Wrow[j]);
        a4 = *reinterpret_cast<const float4*>(&Arow[j]);
    };

    // Stage one tile of tables. jr (tile-relative j) lives at sS[jr&3][jr>>2];
    // waves 0-1 stage sin, waves 2-3 stage cos (wave-uniform branch).
    auto stage_tile = [&](int tile) {
        const int t = tid & 127;
        if constexpr (USE_TABLE) {
            const float4* __restrict__ src = (tid < 128) ? sT : cT;
            float4 (*dst)[kTJ / 4] = (tid < 128) ? sS : sC;
            #pragma unroll
            for (int u = 0; u < 4; ++u)
                dst[u][t] = src[tile * kTJ + 4 * t + u];
        } else {
            #pragma unroll
            for (int u = 0; u < 4; ++u) {
                const int j = tile * kTJ + 4 * t + u;
                const float4 t4 = *reinterpret_cast<const float4*>(&thetaB[(size_t)j * kD]);
                float4 sv, cv;
                __sincosf(t4.x, &sv.x, &cv.x);
                __sincosf(t4.y, &sv.y, &cv.y);
                __sincosf(t4.z, &sv.z, &cv.z);
                __sincosf(t4.w, &sv.w, &cv.w);
                if (tid < 128) sS[u][t] = sv; else sC[u][t] = cv;
            }
        }
    };

    // Compute one stage (4 j per lane) from LDS tile half k in {0,1}.
    auto compute = [&](int k, const float4 w4, const float4 a4) {
        const int idx = k * 64 + lane;               // ds addr stride 16B: no conflict
        const float4 s0 = sS[0][idx], s1 = sS[1][idx], s2 = sS[2][idx], s3 = sS[3][idx];
        const float4 c0 = sC[0][idx], c1 = sC[1][idx], c2 = sC[2][idx], c3 = sC[3][idx];
        float sa, ca;
        float P0, Q0, P1, Q1, P2, Q2, P3, Q3;
        __sincosf(a4.x, &sa, &ca); P0 = w4.x * ca; Q0 = w4.x * sa;
        __sincosf(a4.y, &sa, &ca); P1 = w4.y * ca; Q1 = w4.y * sa;
        __sincosf(a4.z, &sa, &ca); P2 = w4.z * ca; Q2 = w4.z * sa;
        __sincosf(a4.w, &sa, &ca); P3 = w4.w * ca; Q3 = w4.w * sa;
        #define ACC(p, q, s4v, c4v)                                  \
            U[0] = fmaf(p, s4v.x, fmaf(-(q), c4v.x, U[0]));          \
            V[0] = fmaf(p, c4v.x, fmaf( (q), s4v.x, V[0]));          \
            U[1] = fmaf(p, s4v.y, fmaf(-(q), c4v.y, U[1]));          \
            V[1] = fmaf(p, c4v.y, fmaf( (q), s4v.y, V[1]));          \
            U[2] = fmaf(p, s4v.z, fmaf(-(q), c4v.z, U[2]));          \
            V[2] = fmaf(p, c4v.z, fmaf( (q), s4v.z, V[2]));          \
            U[3] = fmaf(p, s4v.w, fmaf(-(q), c4v.w, U[3]));          \
            V[3] = fmaf(p, c4v.w, fmaf( (q), s4v.w, V[3]));
        ACC(P0, Q0, s0, c0)
        ACC(P1, Q1, s1, c1)
        ACC(P2, Q2, s2, c2)
        ACC(P3, Q3, s3, c3)
        #undef ACC
    };

    float4 wB0, aB0, wB1, aB1, wC0, aC0, wC1, aC1;
    pf(0, wB0, aB0);
    pf(1, wB1, aB1);

    #pragma unroll
    for (int tile = 0; tile < kTiles; ++tile) {
        __syncthreads();                  // previous tile's LDS reads done
        stage_tile(tile);
        __syncthreads();
        const int s  = 2 * tile;
        const int p0 = (s + 2 < kStages) ? s + 2 : s;       // clamped (harmless reload)
        const int p1 = (s + 3 < kStages) ? s + 3 : s + 1;
        pf(p0, wC0, aC0);
        pf(p1, wC1, aC1);
        __builtin_amdgcn_sched_barrier(0);   // pin next-tile prefetch above compute
        compute(0, wB0, aB0);
        compute(1, wB1, aB1);
        __builtin_amdgcn_sched_barrier(0);
        wB0 = wC0; aB0 = aC0; wB1 = wC1; aB1 = aC1;   // renamed away (full unroll)
    }

    // Wave-wide butterfly reduction (8 accumulators per wave).
    #pragma unroll
    for (int m = 1; m < 64; m <<= 1) {
        #pragma unroll
        for (int d = 0; d < kD; ++d) {
            U[d] += __shfl_xor(U[d], m, 64);
            V[d] += __shfl_xor(V[d], m, 64);
        }
    }

    if (lane == 0) {
        const float4 t4 = *reinterpret_cast<const float4*>(&theta[(size_t)row * kD]);
        const float4 g4 = *reinterpret_cast<const float4*>(&gam[(size_t)row * kD]);
        const float tv[4] = {t4.x, t4.y, t4.z, t4.w};
        const float gv[4] = {g4.x, g4.y, g4.z, g4.w};
        constexpr float scale = 1.0f / (float)kN;        // GLOBAL_COUPLING / N
        float x[4];
        float nsq = 0.f;
        #pragma unroll
        for (int d = 0; d < kD; ++d) {
            float si, ci;
            __sincosf(tv[d], &si, &ci);
            const float coup = scale * (ci * U[d] - si * V[d]);
            x[d] = gv[d] + coup;          // gamma + coupling (drive cancels theta)
            nsq += x[d] * x[d];
        }
        const float inv = 1.0f / fmaxf(sqrtf(nsq), 1e-6f);
        float4 o;
        o.x = x[0] * inv; o.y = x[1] * inv; o.z = x[2] * inv; o.w = x[3] * inv;
        *reinterpret_cast<float4*>(&out[(size_t)row * kD]) = o;
    }
}

extern "C" void kernel_launch(void* const* d_in, const int* in_sizes, int n_in,
                              void* d_out, int out_size, void* d_ws, size_t ws_size,
                              hipStream_t stream) {
    const float* theta = (const float*)d_in[0];   // (B,N,D) f32
    const float* gam   = (const float*)d_in[1];   // (B,N,D) f32
    const float* W     = (const float*)d_in[2];   // (B,N,N) f32
    const float* alpha = (const float*)d_in[3];   // (B,N,N) f32
    float* out = (float*)d_out;                   // (B,N,D) f32

    const int totalRows = in_sizes[0] / kD;       // B*N = 8192
    const int nblocks = totalRows / 4;            // 2048 (4 rows/block)
    const size_t tabEntries = (size_t)kB * kN;    // 8192 float4 per table
    const size_t needWs = 2 * tabEntries * sizeof(float4);   // 256 KB

    if (ws_size >= needWs) {
        float4* sinT = (float4*)d_ws;
        float4* cosT = sinT + tabEntries;
        table_kernel<<<(int)(tabEntries / 256), 256, 0, stream>>>(theta, sinT, cosT);
        kuramoto_kernel<true><<<nblocks, kBlock, 0, stream>>>(
            theta, gam, W, alpha, sinT, cosT, out);
    } else {
        kuramoto_kernel<false><<<nblocks, kBlock, 0, stream>>>(
            theta, gam, W, alpha, nullptr, nullptr, out);
    }
}